// Round 11
// baseline (19.552 us; speedup 1.0000x reference)
//
#include <hip/hip_runtime.h>

// out[b,i,j,c] = sum_d tanh(start[b,c,i,d] + end[b,c,j,d]) * v[d]
// B=2, C=8, L=256, D=128.
//
// tanh(x) = 1 - 2/(e^{2x}+1);  e^{2(s+e)} = Es*Ee, Es=exp2(K*s), K=2*log2(e).
// u-substitution with the -2 folded in:  W_d = -0.5/v_d,
//   u_d = fma(Es*W_d, Ee, W_d) = -0.5*q_d/v_d,  q_d = EsEe+1
//   => out = sum(v) + sum_d 1/u_d,  and per d-quad all four 1/u merge into
//   ONE rcp: [cd*(u0+u1) + ab*(u2+u3)] / (ab*cd).
// Range: |u| >= 5; worst |ab*cd| ~ 5e24 << f32max.
//
// R11 structure: ONE 64x64 tile per CU (1024 thr, 16 waves = 4 quadrants x
// 4 d-quarters). Same inner loop & occupancy as R10 (4 waves/SIMD, 4x4
// blocking, 2 B/elem LDS, conflict-free strided reads, lane-stride-1
// epilogue), but staging bytes + exp2 per CU HALVE and fetch amplification
// drops 8x -> 4x. m07 calibration: sustained clock ~1.6 GHz under VALU
// load; inner VALU ~9.6 us is the dominant floor term.

#define LDIM 256
#define DDIM 128
#define DPAD 132   // 132 mod 32 = 4: 8 strided rows hit 32 banks exactly once

__global__ __launch_bounds__(1024) void span_tanh_dot_kernel(
    const float* __restrict__ start_h,
    const float* __restrict__ end_h,
    const float* __restrict__ v,
    float* __restrict__ out,
    int C)
{
    __shared__ float pool[2 * 64 * DPAD];   // s tile | e tile ; aliased park buf
    __shared__ float W_s[DDIM];             // -0.5 / v[d]
    __shared__ float s_vsum;

    float* s_t = pool;                      // 64 x DPAD
    float* e_t = pool + 64 * DPAD;          // 64 x DPAD

    const int bc = blockIdx.z;              // b*C + c
    const int i0 = blockIdx.y * 64;
    const int j0 = blockIdx.x * 64;
    const int tx = threadIdx.x;             // 0..7
    const int ty = threadIdx.y;             // 0..7
    const int wz = threadIdx.z;             // 0..15 (wave id)
    const int t  = ty * 8 + tx;             // lane in wave
    const int tid = wz * 64 + t;

    const int q  = wz & 3;                  // quadrant (2x2 of 32x32)
    const int h  = wz >> 2;                 // d-quarter
    const int qi = q >> 1, qj = q & 1;

    const float K = 2.8853900817779268f;    // 2*log2(e)

    const float* sg = start_h + ((size_t)bc * LDIM + i0) * DDIM;
    const float* eg = end_h   + ((size_t)bc * LDIM + j0) * DDIM;

    // W table
    if (tid < 32) {
        const float4 vv = *(const float4*)(v + 4 * tid);
        float4 w;
        w.x = -0.5f * __builtin_amdgcn_rcpf(vv.x);
        w.y = -0.5f * __builtin_amdgcn_rcpf(vv.y);
        w.z = -0.5f * __builtin_amdgcn_rcpf(vv.z);
        w.w = -0.5f * __builtin_amdgcn_rcpf(vv.w);
        *(float4*)(&W_s[4 * tid]) = w;
    }

    // stage 64x128 tiles: s_t = exp2(K*s) * W_d ; e_t = exp2(K*e)
    // 2048 float4 chunks per tensor, 2 per thread. Coalesced.
    #pragma unroll
    for (int k = 0; k < 2; ++k) {
        const int idx = tid + k * 1024;
        const int r  = idx >> 5;
        const int c4 = (idx & 31) << 2;
        const float4 vv = *(const float4*)(v + c4);
        float4 a = *(const float4*)(sg + r * DDIM + c4);
        a.x = __builtin_amdgcn_exp2f(K * a.x) * (-0.5f * __builtin_amdgcn_rcpf(vv.x));
        a.y = __builtin_amdgcn_exp2f(K * a.y) * (-0.5f * __builtin_amdgcn_rcpf(vv.y));
        a.z = __builtin_amdgcn_exp2f(K * a.z) * (-0.5f * __builtin_amdgcn_rcpf(vv.z));
        a.w = __builtin_amdgcn_exp2f(K * a.w) * (-0.5f * __builtin_amdgcn_rcpf(vv.w));
        *(float4*)(&s_t[r * DPAD + c4]) = a;
        float4 b = *(const float4*)(eg + r * DDIM + c4);
        b.x = __builtin_amdgcn_exp2f(K * b.x);
        b.y = __builtin_amdgcn_exp2f(K * b.y);
        b.z = __builtin_amdgcn_exp2f(K * b.z);
        b.w = __builtin_amdgcn_exp2f(K * b.w);
        *(float4*)(&e_t[r * DPAD + c4]) = b;
    }

    // sum(v): wave 0 butterfly -> LDS broadcast
    if (wz == 0) {
        float2 vv = *(const float2*)(v + 2 * t);
        float p = vv.x + vv.y;
        #pragma unroll
        for (int off = 1; off < 64; off <<= 1) p += __shfl_xor(p, off);
        if (t == 0) s_vsum = p;
    }
    __syncthreads();

    const int dbase = __builtin_amdgcn_readfirstlane(h) * 32;  // wave-uniform
    const float* srow = s_t + (qi * 32 + ty) * DPAD;
    const float* erow = e_t + (qj * 32 + tx) * DPAD;

    float acc00 = 0.f, acc01 = 0.f, acc02 = 0.f, acc03 = 0.f;
    float acc10 = 0.f, acc11 = 0.f, acc12 = 0.f, acc13 = 0.f;
    float acc20 = 0.f, acc21 = 0.f, acc22 = 0.f, acc23 = 0.f;
    float acc30 = 0.f, acc31 = 0.f, acc32 = 0.f, acc33 = 0.f;

#define QUAD(ACC, S, E)                                            \
    {                                                              \
        float u0 = fmaf((S).x, (E).x, W.x);                        \
        float u1 = fmaf((S).y, (E).y, W.y);                        \
        float u2 = fmaf((S).z, (E).z, W.z);                        \
        float u3 = fmaf((S).w, (E).w, W.w);                        \
        float ab = u0 * u1, cd = u2 * u3;                          \
        float n01 = u0 + u1;                                       \
        float n23 = u2 + u3;                                       \
        float N = fmaf(n01, cd, n23 * ab);                         \
        float r = __builtin_amdgcn_rcpf(ab * cd);                  \
        ACC = fmaf(N, r, ACC);                                     \
    }

    #pragma unroll 2
    for (int it = 0; it < 8; ++it) {
        const int d = dbase + it * 4;
        const float4 W  = *(const float4*)(&W_s[d]);            // broadcast: free
        const float4 s0 = *(const float4*)(srow + d);           // 8 addrs, 32 banks
        const float4 s1 = *(const float4*)(srow +  8 * DPAD + d);
        const float4 s2 = *(const float4*)(srow + 16 * DPAD + d);
        const float4 s3 = *(const float4*)(srow + 24 * DPAD + d);
        const float4 e0 = *(const float4*)(erow + d);
        const float4 e1 = *(const float4*)(erow +  8 * DPAD + d);
        const float4 e2 = *(const float4*)(erow + 16 * DPAD + d);
        const float4 e3 = *(const float4*)(erow + 24 * DPAD + d);

        QUAD(acc00, s0, e0); QUAD(acc01, s0, e1); QUAD(acc02, s0, e2); QUAD(acc03, s0, e3);
        QUAD(acc10, s1, e0); QUAD(acc11, s1, e1); QUAD(acc12, s1, e2); QUAD(acc13, s1, e3);
        QUAD(acc20, s2, e0); QUAD(acc21, s2, e1); QUAD(acc22, s2, e2); QUAD(acc23, s2, e3);
        QUAD(acc30, s3, e0); QUAD(acc31, s3, e1); QUAD(acc32, s3, e2); QUAD(acc33, s3, e3);
    }
#undef QUAD

    // ---- cross-wave d-reduction, aliased into pool, lane-stride-1 ----
    __syncthreads();                        // all tile reads done
    float* park = pool;                     // needs 16384 floats <= 16896
#define PK(A, B, ACC) park[((((q * 4 + h) * 4 + (A)) * 4 + (B)) * 64) + t] = ACC;
    PK(0,0,acc00) PK(0,1,acc01) PK(0,2,acc02) PK(0,3,acc03)
    PK(1,0,acc10) PK(1,1,acc11) PK(1,2,acc12) PK(1,3,acc13)
    PK(2,0,acc20) PK(2,1,acc21) PK(2,2,acc22) PK(2,3,acc23)
    PK(3,0,acc30) PK(3,1,acc31) PK(3,2,acc32) PK(3,3,acc33)
#undef PK
    __syncthreads();

    // wave (q,h) combines row-group a = h of quadrant q
#define COMB(B)                                                        \
    (park[(((q * 4 + 0) * 4 + h) * 4 + (B)) * 64 + t] +                \
     park[(((q * 4 + 1) * 4 + h) * 4 + (B)) * 64 + t] +                \
     park[(((q * 4 + 2) * 4 + h) * 4 + (B)) * 64 + t] +                \
     park[(((q * 4 + 3) * 4 + h) * 4 + (B)) * 64 + t])
    const float o0 = COMB(0);
    const float o1 = COMB(1);
    const float o2 = COMB(2);
    const float o3 = COMB(3);
#undef COMB

    const int b_ = bc / C;
    const int c_ = bc - b_ * C;
    const float Sv = s_vsum;
    const int i = i0 + qi * 32 + ty + 8 * h;
    const int j = j0 + qj * 32 + tx;
    const size_t rowbase = (((size_t)b_ * LDIM + i) * LDIM) * C + c_;
    out[rowbase + (size_t)(j     ) * C] = Sv + o0;
    out[rowbase + (size_t)(j +  8) * C] = Sv + o1;
    out[rowbase + (size_t)(j + 16) * C] = Sv + o2;
    out[rowbase + (size_t)(j + 24) * C] = Sv + o3;
}

extern "C" void kernel_launch(void* const* d_in, const int* in_sizes, int n_in,
                              void* d_out, int out_size, void* d_ws, size_t ws_size,
                              hipStream_t stream) {
    const float* start_h = (const float*)d_in[0];
    const float* end_h   = (const float*)d_in[1];
    const float* v       = (const float*)d_in[2];
    float* out = (float*)d_out;

    const int BC = in_sizes[0] / (LDIM * DDIM);  // B*C = 16
    const int C  = 8;

    dim3 grid(LDIM / 64, LDIM / 64, BC);   // (4, 4, 16) = 256 blocks = 1/CU
    dim3 block(8, 8, 16);                  // 1024 threads = 16 waves
    span_tanh_dot_kernel<<<grid, block, 0, stream>>>(start_h, end_h, v, out, C);
}